// Round 8
// baseline (338.834 us; speedup 1.0000x reference)
//
#include <hip/hip_runtime.h>

// GraphSAGE 2-layer pipeline, fp16 activations + MFMA f16 (weights hi+lo 2-term).
// linear_pre fused into conv_first:  t1 = x@(Wpre@Wl1)+b_pre@Wl1, r1 = x@(Wpre@Wr1)+b_pre@Wr1.
// GEMMs are loop-free: one 64-row tile per block-group, grid sized to fill
// 32 waves/CU (round-7 lesson: compiler targets 8 waves/SIMD & ~56 VGPR;
// a 512-block grid only provided 2 waves/SIMD -> latency-exposed).
// N=50000, E=600000, edge_index int32.

#define NN   50000
#define EE   600000
#define NBLK 49          // ceil(NN/1024)
#define NRG64 782        // ceil(NN/64)

typedef __attribute__((ext_vector_type(8))) _Float16 h8v;
typedef __attribute__((ext_vector_type(4))) _Float16 h4v;
typedef __attribute__((ext_vector_type(2))) _Float16 h2v;
typedef __attribute__((ext_vector_type(8))) short short8v;
typedef __attribute__((ext_vector_type(4))) float f32x4;

__device__ inline h8v h8zero() {
    return __builtin_bit_cast(h8v, (short8v){0,0,0,0,0,0,0,0});
}

// ---------------- CSR build ----------------

__global__ __launch_bounds__(256) void k_count(const int* __restrict__ ei,
                                               int* __restrict__ counts) {
    int e = blockIdx.x * 256 + threadIdx.x;
    if (e < EE) atomicAdd(&counts[ei[EE + e]], 1);
}

__global__ __launch_bounds__(256) void k_scan_a(const int* __restrict__ counts,
                                                int* __restrict__ bsums) {
    int b = blockIdx.x, t = threadIdx.x;
    int idx = b * 1024 + t * 4;
    int s = 0;
#pragma unroll
    for (int j = 0; j < 4; ++j)
        if (idx + j < NN) s += counts[idx + j];
#pragma unroll
    for (int off = 32; off > 0; off >>= 1) s += __shfl_down(s, off);
    __shared__ int ls[4];
    if ((t & 63) == 0) ls[t >> 6] = s;
    __syncthreads();
    if (t == 0) bsums[b] = ls[0] + ls[1] + ls[2] + ls[3];
}

__global__ void k_scan_b(int* __restrict__ bsums) {
    int t = threadIdx.x;                       // 64 threads
    int v = (t < NBLK) ? bsums[t] : 0;
    int orig = v;
#pragma unroll
    for (int off = 1; off < 64; off <<= 1) {
        int u = __shfl_up(v, off);
        if (t >= off) v += u;
    }
    if (t < NBLK) bsums[t] = v - orig;          // exclusive
}

__global__ __launch_bounds__(256) void k_scan_c(const int* __restrict__ counts,
                                                const int* __restrict__ bsums,
                                                int* __restrict__ rowp) {
    int b = blockIdx.x, t = threadIdx.x;
    int lane = t & 63, wave = t >> 6;
    int idx = b * 1024 + t * 4;
    int c[4], s = 0;
#pragma unroll
    for (int j = 0; j < 4; ++j) {
        c[j] = (idx + j < NN) ? counts[idx + j] : 0;
        s += c[j];
    }
    int sv = s;
#pragma unroll
    for (int off = 1; off < 64; off <<= 1) {
        int u = __shfl_up(sv, off);
        if (lane >= off) sv += u;
    }
    __shared__ int lsum[4];
    if (lane == 63) lsum[wave] = sv;
    __syncthreads();
    int woff = 0;
    for (int wv = 0; wv < wave; ++wv) woff += lsum[wv];
    int base = bsums[b] + woff + (sv - s);
#pragma unroll
    for (int j = 0; j < 4; ++j) {
        if (idx + j < NN) { rowp[idx + j] = base; base += c[j]; }
    }
}

__global__ __launch_bounds__(256) void k_scatter(const int* __restrict__ ei,
                                                 const int* __restrict__ rowp,
                                                 int* __restrict__ cursor,
                                                 int* __restrict__ col) {
    int e = blockIdx.x * 256 + threadIdx.x;
    if (e < EE) {
        int d = ei[EE + e];
        int p = atomicAdd(&cursor[d], 1);
        col[rowp[d] + p] = ei[e];
    }
}

// ---------------- x: fp32 -> fp16 ----------------

__global__ __launch_bounds__(256) void k_cvt(const float* __restrict__ in,
                                             _Float16* __restrict__ outp, int n4) {
    int i = blockIdx.x * 256 + threadIdx.x;
    if (i >= n4) return;
    float4 v = ((const float4*)in)[i];
    h4v o;
    o[0] = (_Float16)v.x; o[1] = (_Float16)v.y;
    o[2] = (_Float16)v.z; o[3] = (_Float16)v.w;
    ((h4v*)outp)[i] = o;
}

// ---- prep: fused layer-1 weights (WA=Wpre@Wl1, WB=Wpre@Wr1, transposed hi/lo
// ---- fp16) + bias rows (fp32) + layer-2 packed transposed hi/lo weights.

__global__ __launch_bounds__(256) void k_prep(const float* __restrict__ Wpre,
                                              const float* __restrict__ bpre,
                                              const float* __restrict__ Wl1,
                                              const float* __restrict__ Wr1,
                                              const float* __restrict__ Wl2,
                                              const float* __restrict__ Wr2,
                                              _Float16* __restrict__ WAH,
                                              _Float16* __restrict__ WAL,
                                              _Float16* __restrict__ WBH,
                                              _Float16* __restrict__ WBL,
                                              float* __restrict__ bA,
                                              float* __restrict__ bB,
                                              _Float16* __restrict__ W2lH,
                                              _Float16* __restrict__ W2lL,
                                              _Float16* __restrict__ W2rH,
                                              _Float16* __restrict__ W2rL) {
    int idx = blockIdx.x * 256 + threadIdx.x;     // 321*256 = 82176 exact
    if (idx < 65792) {                            // 2*257*128: layer-1 fuse
        int which = idx / (257 * 128);
        int rem = idx - which * 257 * 128;
        int i = rem >> 7, j = rem & 127;
        const float* W = which ? Wr1 : Wl1;
        float s = 0.f;
        if (i < 256) {
#pragma unroll 4
            for (int k = 0; k < 128; ++k) s += Wpre[i * 128 + k] * W[k * 128 + j];
            _Float16 h = (_Float16)s;
            _Float16 l = (_Float16)(s - (float)h);
            if (which) { WBH[j * 256 + i] = h; WBL[j * 256 + i] = l; }
            else       { WAH[j * 256 + i] = h; WAL[j * 256 + i] = l; }
        } else {
#pragma unroll 4
            for (int k = 0; k < 128; ++k) s += bpre[k] * W[k * 128 + j];
            if (which) bB[j] = s; else bA[j] = s;
        }
    } else {                                      // 2*8192: layer-2 pack
        int idx2 = idx - 65792;
        int which = idx2 >> 13;
        int rem = idx2 & 8191;
        int k = rem >> 6, m = rem & 63;
        float w = (which ? Wr2 : Wl2)[rem];
        _Float16 h = (_Float16)w;
        _Float16 l = (_Float16)(w - (float)h);
        if (which) { W2rH[m * 128 + k] = h; W2rL[m * 128 + k] = l; }
        else       { W2lH[m * 128 + k] = h; W2lL[m * 128 + k] = l; }
    }
}

// ---- fused dual GEMM: t1 = xh@WA + bA, r1 = xh@WB + bB  (K=256) -------------
// Loop-free: block-group of 4 blocks covers 16 slices x one 64-row tile.
// Grid = NRG64*4 = 3128 blocks -> 12512 waves (fills 32 waves/CU).

__global__ __launch_bounds__(256) void k_gemm_fused(
        const _Float16* __restrict__ xh,
        const _Float16* __restrict__ WAH, const _Float16* __restrict__ WAL,
        const _Float16* __restrict__ WBH, const _Float16* __restrict__ WBL,
        const float* __restrict__ bA, const float* __restrict__ bB,
        _Float16* __restrict__ t1, _Float16* __restrict__ r1) {
    const int wave = threadIdx.x >> 6, lane = threadIdx.x & 63;
    const int r = lane & 15, kb = lane >> 4;
    const int s = ((blockIdx.x & 3) << 2) + wave;   // 0..15
    const int sel = s >> 3;                         // 0 -> t1, 1 -> r1
    const int col = ((s & 7) << 4) + r;
    const _Float16* __restrict__ WH = sel ? WBH : WAH;
    const _Float16* __restrict__ WL = sel ? WBL : WAL;
    _Float16* __restrict__ dst = sel ? r1 : t1;
    const float bias = (sel ? bB : bA)[col];
    const int row0 = (blockIdx.x >> 2) << 6;

    f32x4 acc[4];
#pragma unroll
    for (int a = 0; a < 4; ++a) acc[a] = (f32x4){0.f, 0.f, 0.f, 0.f};

#pragma unroll
    for (int k = 0; k < 8; ++k) {
        size_t woff = (size_t)col * 256 + k * 32 + kb * 8;
        h8v wh = *(const h8v*)&WH[woff];
        h8v wl = *(const h8v*)&WL[woff];
        h8v a[4];
#pragma unroll
        for (int rt = 0; rt < 4; ++rt) {
            int rr = row0 + rt * 16;                // tile-uniform validity
            a[rt] = (rr < NN)
                ? *(const h8v*)&xh[(size_t)(rr + r) * 256 + k * 32 + kb * 8]
                : h8zero();
        }
#pragma unroll
        for (int rt = 0; rt < 4; ++rt) {
            acc[rt] = __builtin_amdgcn_mfma_f32_16x16x32_f16(a[rt], wh, acc[rt], 0, 0, 0);
            acc[rt] = __builtin_amdgcn_mfma_f32_16x16x32_f16(a[rt], wl, acc[rt], 0, 0, 0);
        }
    }
#pragma unroll
    for (int rt = 0; rt < 4; ++rt) {
        int rr = row0 + rt * 16;
        if (rr >= NN) continue;
        int rbase = rr + kb * 4;                    // C: row = 4*(lane>>4)+reg
#pragma unroll
        for (int j = 0; j < 4; ++j)
            dst[(size_t)(rbase + j) * 128 + col] = (_Float16)(acc[rt][j] + bias);
    }
}

// ---- layer-2 dual GEMM: t2 = h1@Wl2, r2 = h1@Wr2  (K=128, M=64) -------------
// Loop-free: block-group of 2 blocks covers 8 slices x one 64-row tile.
// Grid = NRG64*2 = 1564 blocks.

__global__ __launch_bounds__(256) void k_gemm_dual2(
        const _Float16* __restrict__ A,
        const _Float16* __restrict__ W1H, const _Float16* __restrict__ W1L,
        const _Float16* __restrict__ W2H, const _Float16* __restrict__ W2L,
        _Float16* __restrict__ T, _Float16* __restrict__ R) {
    const int wave = threadIdx.x >> 6, lane = threadIdx.x & 63;
    const int r = lane & 15, kb = lane >> 4;
    const int s = ((blockIdx.x & 1) << 2) + wave;   // 0..7
    const int sel = s >> 2;                         // 0 -> T, 1 -> R
    const int col = ((s & 3) << 4) + r;
    const _Float16* __restrict__ WH = sel ? W2H : W1H;
    const _Float16* __restrict__ WL = sel ? W2L : W1L;
    _Float16* __restrict__ dst = sel ? R : T;
    const int row0 = (blockIdx.x >> 1) << 6;

    f32x4 acc[4];
#pragma unroll
    for (int a = 0; a < 4; ++a) acc[a] = (f32x4){0.f, 0.f, 0.f, 0.f};

#pragma unroll
    for (int k = 0; k < 4; ++k) {
        size_t woff = (size_t)col * 128 + k * 32 + kb * 8;
        h8v wh = *(const h8v*)&WH[woff];
        h8v wl = *(const h8v*)&WL[woff];
        h8v a[4];
#pragma unroll
        for (int rt = 0; rt < 4; ++rt) {
            int rr = row0 + rt * 16;
            a[rt] = (rr < NN)
                ? *(const h8v*)&A[(size_t)(rr + r) * 128 + k * 32 + kb * 8]
                : h8zero();
        }
#pragma unroll
        for (int rt = 0; rt < 4; ++rt) {
            acc[rt] = __builtin_amdgcn_mfma_f32_16x16x32_f16(a[rt], wh, acc[rt], 0, 0, 0);
            acc[rt] = __builtin_amdgcn_mfma_f32_16x16x32_f16(a[rt], wl, acc[rt], 0, 0, 0);
        }
    }
#pragma unroll
    for (int rt = 0; rt < 4; ++rt) {
        int rr = row0 + rt * 16;
        if (rr >= NN) continue;
        int rbase = rr + kb * 4;
#pragma unroll
        for (int j = 0; j < 4; ++j)
            dst[(size_t)(rbase + j) * 64 + col] = (_Float16)acc[rt][j];
    }
}

// ------- Aggregation 1: h1 = fp16(relu(mean(t1[src]) + bl1 + r1)) -------------
// one wave per node; two 32-lane halves, h4v (8B) loads, 2 neighbors/step.

__global__ __launch_bounds__(256) void k_aggr1(const _Float16* __restrict__ t1,
                                               const _Float16* __restrict__ r1,
                                               const int* __restrict__ rowp,
                                               const int* __restrict__ counts,
                                               const int* __restrict__ col,
                                               const float* __restrict__ bl1,
                                               _Float16* __restrict__ h1) {
    int node = blockIdx.x * 4 + (threadIdx.x >> 6);
    int lane = threadIdx.x & 63;
    if (node >= NN) return;
    int half = lane >> 5, sl = lane & 31;
    int e0 = rowp[node], cnt = counts[node];
    float a0 = 0.f, a1 = 0.f, a2 = 0.f, a3 = 0.f;
    const h4v* T = (const h4v*)t1;                 // 32 h4v per row
    for (int base = 0; base < cnt; base += 64) {
        int m = cnt - base; if (m > 64) m = 64;
        int myS = (base + lane < cnt) ? col[e0 + base + lane] : 0;
        int i = 0;
        for (; i + 8 <= m; i += 8) {
            int s0 = __shfl(myS, i + 0 + half), s1 = __shfl(myS, i + 2 + half);
            int s2 = __shfl(myS, i + 4 + half), s3 = __shfl(myS, i + 6 + half);
            h4v v0 = T[(size_t)s0 * 32 + sl], v1 = T[(size_t)s1 * 32 + sl];
            h4v v2 = T[(size_t)s2 * 32 + sl], v3 = T[(size_t)s3 * 32 + sl];
            a0 += (float)v0[0] + (float)v1[0] + (float)v2[0] + (float)v3[0];
            a1 += (float)v0[1] + (float)v1[1] + (float)v2[1] + (float)v3[1];
            a2 += (float)v0[2] + (float)v1[2] + (float)v2[2] + (float)v3[2];
            a3 += (float)v0[3] + (float)v1[3] + (float)v2[3] + (float)v3[3];
        }
        for (; i < m; i += 2) {
            if (i + half < m) {
                int s = __shfl(myS, i + half);
                h4v v = T[(size_t)s * 32 + sl];
                a0 += (float)v[0]; a1 += (float)v[1];
                a2 += (float)v[2]; a3 += (float)v[3];
            }
        }
    }
    a0 += __shfl_xor(a0, 32); a1 += __shfl_xor(a1, 32);
    a2 += __shfl_xor(a2, 32); a3 += __shfl_xor(a3, 32);
    float di = (cnt > 0) ? 1.0f / (float)cnt : 0.0f;
    h4v rr = ((const h4v*)r1)[(size_t)node * 32 + sl];
    float4 bb = ((const float4*)bl1)[sl];
    if (half == 0) {
        h4v h;
        h[0] = (_Float16)fmaxf(fmaf(a0, di, bb.x + (float)rr[0]), 0.0f);
        h[1] = (_Float16)fmaxf(fmaf(a1, di, bb.y + (float)rr[1]), 0.0f);
        h[2] = (_Float16)fmaxf(fmaf(a2, di, bb.z + (float)rr[2]), 0.0f);
        h[3] = (_Float16)fmaxf(fmaf(a3, di, bb.w + (float)rr[3]), 0.0f);
        ((h4v*)h1)[(size_t)node * 32 + sl] = h;
    }
}

// ------- Aggregation 2 + L2 normalize -----------------------------------------

__global__ __launch_bounds__(256) void k_aggr2(const _Float16* __restrict__ t2,
                                               const _Float16* __restrict__ r2,
                                               const int* __restrict__ rowp,
                                               const int* __restrict__ counts,
                                               const int* __restrict__ col,
                                               const float* __restrict__ bl2,
                                               float* __restrict__ out) {
    int node = blockIdx.x * 4 + (threadIdx.x >> 6);
    int lane = threadIdx.x & 63;
    if (node >= NN) return;
    int half = lane >> 5, sl = lane & 31;
    int e0 = rowp[node], cnt = counts[node];
    float ax = 0.f, ay = 0.f;
    const h2v* T = (const h2v*)t2;
    for (int base = 0; base < cnt; base += 64) {
        int m = cnt - base; if (m > 64) m = 64;
        int myS = (base + lane < cnt) ? col[e0 + base + lane] : 0;
        int i = 0;
        for (; i + 8 <= m; i += 8) {
            int s0 = __shfl(myS, i + 0 + half), s1 = __shfl(myS, i + 2 + half);
            int s2 = __shfl(myS, i + 4 + half), s3 = __shfl(myS, i + 6 + half);
            h2v v0 = T[(size_t)s0 * 32 + sl], v1 = T[(size_t)s1 * 32 + sl];
            h2v v2 = T[(size_t)s2 * 32 + sl], v3 = T[(size_t)s3 * 32 + sl];
            ax += (float)v0[0] + (float)v1[0] + (float)v2[0] + (float)v3[0];
            ay += (float)v0[1] + (float)v1[1] + (float)v2[1] + (float)v3[1];
        }
        for (; i < m; i += 2) {
            if (i + half < m) {
                int s = __shfl(myS, i + half);
                h2v v = T[(size_t)s * 32 + sl];
                ax += (float)v[0]; ay += (float)v[1];
            }
        }
    }
    ax += __shfl_xor(ax, 32);
    ay += __shfl_xor(ay, 32);
    float di = (cnt > 0) ? 1.0f / (float)cnt : 0.0f;
    h2v rr = ((const h2v*)r2)[(size_t)node * 32 + sl];
    float2 bb = ((const float2*)bl2)[sl];
    float v0 = fmaf(ax, di, bb.x + (float)rr[0]);
    float v1 = fmaf(ay, di, bb.y + (float)rr[1]);
    float ss = v0 * v0 + v1 * v1;
#pragma unroll
    for (int off = 16; off > 0; off >>= 1) ss += __shfl_xor(ss, off);
    float inv = 1.0f / fmaxf(sqrtf(ss), 1e-12f);
    if (half == 0)
        ((float2*)out)[(size_t)node * 32 + sl] = make_float2(v0 * inv, v1 * inv);
}

// ---------------- launch ----------------

extern "C" void kernel_launch(void* const* d_in, const int* in_sizes, int n_in,
                              void* d_out, int out_size, void* d_ws, size_t ws_size,
                              hipStream_t stream) {
    const float* x    = (const float*)d_in[0];
    const int*   ei   = (const int*)d_in[1];
    const float* Wpre = (const float*)d_in[2];
    const float* bpre = (const float*)d_in[3];
    const float* Wl1  = (const float*)d_in[4];
    const float* bl1  = (const float*)d_in[5];
    const float* Wr1  = (const float*)d_in[6];
    const float* Wl2  = (const float*)d_in[7];
    const float* bl2  = (const float*)d_in[8];
    const float* Wr2  = (const float*)d_in[9];
    float* out = (float*)d_out;

    char* w = (char*)d_ws;
    int* counts = (int*)w;  w += (size_t)NN * 4;
    int* cursor = (int*)w;  w += (size_t)NN * 4;
    int* rowp   = (int*)w;  w += (size_t)NN * 4;
    int* bsums  = (int*)w;  w += 256;
    int* col    = (int*)w;  w += (size_t)EE * 4;
    _Float16* WAH  = (_Float16*)w; w += (size_t)256 * 128 * 2;
    _Float16* WAL  = (_Float16*)w; w += (size_t)256 * 128 * 2;
    _Float16* WBH  = (_Float16*)w; w += (size_t)256 * 128 * 2;
    _Float16* WBL  = (_Float16*)w; w += (size_t)256 * 128 * 2;
    float*    bA   = (float*)w;    w += 128 * 4;
    float*    bB   = (float*)w;    w += 128 * 4;
    _Float16* W2lH = (_Float16*)w; w += (size_t)128 * 64 * 2;
    _Float16* W2lL = (_Float16*)w; w += (size_t)128 * 64 * 2;
    _Float16* W2rH = (_Float16*)w; w += (size_t)128 * 64 * 2;
    _Float16* W2rL = (_Float16*)w; w += (size_t)128 * 64 * 2;
    _Float16* xh   = (_Float16*)w; w += (size_t)NN * 256 * 2;   // 25.6MB
    _Float16* t1   = (_Float16*)w; w += (size_t)NN * 128 * 2;   // 12.8MB
    _Float16* r1   = (_Float16*)w; w += (size_t)NN * 128 * 2;
    _Float16* h1   = (_Float16*)w; w += (size_t)NN * 128 * 2;
    _Float16* t2   = (_Float16*)w; w += (size_t)NN * 64 * 2;
    _Float16* r2   = (_Float16*)w; w += (size_t)NN * 64 * 2;

    hipMemsetAsync(counts, 0, (size_t)NN * 8, stream);    // counts + cursor

    dim3 b256(256);
    dim3 gE((EE + 255) / 256);
    k_count<<<gE, b256, 0, stream>>>(ei, counts);
    k_scan_a<<<dim3(NBLK), b256, 0, stream>>>(counts, bsums);
    k_scan_b<<<dim3(1), dim3(64), 0, stream>>>(bsums);
    k_scan_c<<<dim3(NBLK), b256, 0, stream>>>(counts, bsums, rowp);
    k_scatter<<<gE, b256, 0, stream>>>(ei, rowp, cursor, col);

    k_cvt<<<dim3(NN * 256 / 4 / 256), b256, 0, stream>>>(x, xh, NN * 256 / 4);
    k_prep<<<dim3(321), b256, 0, stream>>>(Wpre, bpre, Wl1, Wr1, Wl2, Wr2,
                                           WAH, WAL, WBH, WBL, bA, bB,
                                           W2lH, W2lL, W2rH, W2rL);

    k_gemm_fused<<<dim3(NRG64 * 4), b256, 0, stream>>>(xh, WAH, WAL, WBH, WBL,
                                                       bA, bB, t1, r1);
    k_aggr1<<<dim3((NN + 3) / 4), b256, 0, stream>>>(t1, r1, rowp, counts, col, bl1, h1);
    k_gemm_dual2<<<dim3(NRG64 * 2), b256, 0, stream>>>(h1, W2lH, W2lL, W2rH, W2rL, t2, r2);
    k_aggr2<<<dim3((NN + 3) / 4), b256, 0, stream>>>(t2, r2, rowp, counts, col, bl2, out);
}

// Round 10
// 312.291 us; speedup vs baseline: 1.0850x; 1.0850x over previous
//
#include <hip/hip_runtime.h>

// GraphSAGE 2-layer pipeline, fp16 activations + MFMA f16 (weights hi+lo 2-term).
// linear_pre fused into conv_first:  t1 = x@(Wpre@Wl1)+b_pre@Wl1, r1 = x@(Wpre@Wr1)+b_pre@Wr1.
// Round-9 (resubmit after acquisition timeout): GEMMs stage the A-tile in LDS
// (XOR-swizzled) once per block and cover ALL output columns in-block
// (round-8 failure: every wave re-read the full A tile from L2/HBM -> 16x
// amplification, 410MB traffic, MfmaUtil 6%).
// N=50000, E=600000, edge_index int32.

#define NN   50000
#define EE   600000
#define NBLK 49          // ceil(NN/1024)
#define NRG64 782        // ceil(NN/64)

typedef __attribute__((ext_vector_type(8))) _Float16 h8v;
typedef __attribute__((ext_vector_type(4))) _Float16 h4v;
typedef __attribute__((ext_vector_type(2))) _Float16 h2v;
typedef __attribute__((ext_vector_type(8))) short short8v;
typedef __attribute__((ext_vector_type(4))) float f32x4;

__device__ inline h8v h8zero() {
    return __builtin_bit_cast(h8v, (short8v){0,0,0,0,0,0,0,0});
}

// ---------------- CSR build ----------------

__global__ __launch_bounds__(256) void k_count(const int* __restrict__ ei,
                                               int* __restrict__ counts) {
    int e = blockIdx.x * 256 + threadIdx.x;
    if (e < EE) atomicAdd(&counts[ei[EE + e]], 1);
}

__global__ __launch_bounds__(256) void k_scan_a(const int* __restrict__ counts,
                                                int* __restrict__ bsums) {
    int b = blockIdx.x, t = threadIdx.x;
    int idx = b * 1024 + t * 4;
    int s = 0;
#pragma unroll
    for (int j = 0; j < 4; ++j)
        if (idx + j < NN) s += counts[idx + j];
#pragma unroll
    for (int off = 32; off > 0; off >>= 1) s += __shfl_down(s, off);
    __shared__ int ls[4];
    if ((t & 63) == 0) ls[t >> 6] = s;
    __syncthreads();
    if (t == 0) bsums[b] = ls[0] + ls[1] + ls[2] + ls[3];
}

__global__ void k_scan_b(int* __restrict__ bsums) {
    int t = threadIdx.x;                       // 64 threads
    int v = (t < NBLK) ? bsums[t] : 0;
    int orig = v;
#pragma unroll
    for (int off = 1; off < 64; off <<= 1) {
        int u = __shfl_up(v, off);
        if (t >= off) v += u;
    }
    if (t < NBLK) bsums[t] = v - orig;          // exclusive
}

__global__ __launch_bounds__(256) void k_scan_c(const int* __restrict__ counts,
                                                const int* __restrict__ bsums,
                                                int* __restrict__ rowp) {
    int b = blockIdx.x, t = threadIdx.x;
    int lane = t & 63, wave = t >> 6;
    int idx = b * 1024 + t * 4;
    int c[4], s = 0;
#pragma unroll
    for (int j = 0; j < 4; ++j) {
        c[j] = (idx + j < NN) ? counts[idx + j] : 0;
        s += c[j];
    }
    int sv = s;
#pragma unroll
    for (int off = 1; off < 64; off <<= 1) {
        int u = __shfl_up(sv, off);
        if (lane >= off) sv += u;
    }
    __shared__ int lsum[4];
    if (lane == 63) lsum[wave] = sv;
    __syncthreads();
    int woff = 0;
    for (int wv = 0; wv < wave; ++wv) woff += lsum[wv];
    int base = bsums[b] + woff + (sv - s);
#pragma unroll
    for (int j = 0; j < 4; ++j) {
        if (idx + j < NN) { rowp[idx + j] = base; base += c[j]; }
    }
}

__global__ __launch_bounds__(256) void k_scatter(const int* __restrict__ ei,
                                                 const int* __restrict__ rowp,
                                                 int* __restrict__ cursor,
                                                 int* __restrict__ col) {
    int e = blockIdx.x * 256 + threadIdx.x;
    if (e < EE) {
        int d = ei[EE + e];
        int p = atomicAdd(&cursor[d], 1);
        col[rowp[d] + p] = ei[e];
    }
}

// ---------------- x: fp32 -> fp16 ----------------

__global__ __launch_bounds__(256) void k_cvt(const float* __restrict__ in,
                                             _Float16* __restrict__ outp, int n4) {
    int i = blockIdx.x * 256 + threadIdx.x;
    if (i >= n4) return;
    float4 v = ((const float4*)in)[i];
    h4v o;
    o[0] = (_Float16)v.x; o[1] = (_Float16)v.y;
    o[2] = (_Float16)v.z; o[3] = (_Float16)v.w;
    ((h4v*)outp)[i] = o;
}

// ---- prep: fused layer-1 weights (WA=Wpre@Wl1, WB=Wpre@Wr1, transposed hi/lo
// ---- fp16) + bias rows (fp32) + layer-2 packed transposed hi/lo weights.

__global__ __launch_bounds__(256) void k_prep(const float* __restrict__ Wpre,
                                              const float* __restrict__ bpre,
                                              const float* __restrict__ Wl1,
                                              const float* __restrict__ Wr1,
                                              const float* __restrict__ Wl2,
                                              const float* __restrict__ Wr2,
                                              _Float16* __restrict__ WAH,
                                              _Float16* __restrict__ WAL,
                                              _Float16* __restrict__ WBH,
                                              _Float16* __restrict__ WBL,
                                              float* __restrict__ bA,
                                              float* __restrict__ bB,
                                              _Float16* __restrict__ W2lH,
                                              _Float16* __restrict__ W2lL,
                                              _Float16* __restrict__ W2rH,
                                              _Float16* __restrict__ W2rL) {
    int idx = blockIdx.x * 256 + threadIdx.x;     // 321*256 = 82176 exact
    if (idx < 65792) {                            // 2*257*128: layer-1 fuse
        int which = idx / (257 * 128);
        int rem = idx - which * 257 * 128;
        int i = rem >> 7, j = rem & 127;
        const float* W = which ? Wr1 : Wl1;
        float s = 0.f;
        if (i < 256) {
#pragma unroll 4
            for (int k = 0; k < 128; ++k) s += Wpre[i * 128 + k] * W[k * 128 + j];
            _Float16 h = (_Float16)s;
            _Float16 l = (_Float16)(s - (float)h);
            if (which) { WBH[j * 256 + i] = h; WBL[j * 256 + i] = l; }
            else       { WAH[j * 256 + i] = h; WAL[j * 256 + i] = l; }
        } else {
#pragma unroll 4
            for (int k = 0; k < 128; ++k) s += bpre[k] * W[k * 128 + j];
            if (which) bB[j] = s; else bA[j] = s;
        }
    } else {                                      // 2*8192: layer-2 pack
        int idx2 = idx - 65792;
        int which = idx2 >> 13;
        int rem = idx2 & 8191;
        int k = rem >> 6, m = rem & 63;
        float w = (which ? Wr2 : Wl2)[rem];
        _Float16 h = (_Float16)w;
        _Float16 l = (_Float16)(w - (float)h);
        if (which) { W2rH[m * 128 + k] = h; W2rL[m * 128 + k] = l; }
        else       { W2lH[m * 128 + k] = h; W2lL[m * 128 + k] = l; }
    }
}

// ---- fused dual GEMM: t1 = xh@WA + bA, r1 = xh@WB + bB  (K=256) -------------
// Block = 64 rows, A tile staged once in LDS (swizzled). Waves 0,1 -> t1,
// waves 2,3 -> r1; each wave 4 col-slices of 16. A read from HBM exactly once.

__global__ __launch_bounds__(256) void k_gemm_fused(
        const _Float16* __restrict__ xh,
        const _Float16* __restrict__ WAH, const _Float16* __restrict__ WAL,
        const _Float16* __restrict__ WBH, const _Float16* __restrict__ WBL,
        const float* __restrict__ bA, const float* __restrict__ bB,
        _Float16* __restrict__ t1, _Float16* __restrict__ r1) {
    __shared__ char As[64 * 512];              // 64 rows x 256 fp16, swizzled
    const int t = threadIdx.x;
    const int wave = t >> 6, lane = t & 63;
    const int r = lane & 15, kb = lane >> 4;
    const int row0 = blockIdx.x << 6;

#pragma unroll
    for (int j = 0; j < 8; ++j) {              // stage: 8 x 16B per thread
        int id = t + (j << 8);
        int row = id >> 5, c16 = id & 31;
        int gr = row0 + row;
        h8v v = (gr < NN) ? *(const h8v*)&xh[(size_t)gr * 256 + (c16 << 3)]
                          : h8zero();
        *(h8v*)&As[row * 512 + (((c16 << 4)) ^ ((row & 7) << 4))] = v;
    }
    __syncthreads();

    const int sel = wave >> 1;                 // 0 -> t1, 1 -> r1
    const _Float16* __restrict__ WH = sel ? WBH : WAH;
    const _Float16* __restrict__ WL = sel ? WBL : WAL;
    _Float16* __restrict__ dst = sel ? r1 : t1;
    const float* __restrict__ bias = sel ? bB : bA;
    const int colbase = (wave & 1) << 6;       // 64 cols per wave

    f32x4 acc[4][4];
#pragma unroll
    for (int sl = 0; sl < 4; ++sl)
#pragma unroll
        for (int rt = 0; rt < 4; ++rt) acc[sl][rt] = (f32x4){0.f, 0.f, 0.f, 0.f};

#pragma unroll
    for (int k = 0; k < 8; ++k) {
        h8v a[4];
#pragma unroll
        for (int rt = 0; rt < 4; ++rt) {
            int row = (rt << 4) + r;
            a[rt] = *(const h8v*)&As[row * 512 +
                                     (((k << 6) + (kb << 4)) ^ ((row & 7) << 4))];
        }
#pragma unroll
        for (int sl = 0; sl < 4; ++sl) {
            size_t woff = (size_t)(colbase + (sl << 4) + r) * 256 + (k << 5) + (kb << 3);
            h8v wh = *(const h8v*)&WH[woff];
            h8v wl = *(const h8v*)&WL[woff];
#pragma unroll
            for (int rt = 0; rt < 4; ++rt) {
                acc[sl][rt] = __builtin_amdgcn_mfma_f32_16x16x32_f16(a[rt], wh, acc[sl][rt], 0, 0, 0);
                acc[sl][rt] = __builtin_amdgcn_mfma_f32_16x16x32_f16(a[rt], wl, acc[sl][rt], 0, 0, 0);
            }
        }
    }
#pragma unroll
    for (int sl = 0; sl < 4; ++sl) {
        int col = colbase + (sl << 4) + r;
        float b = bias[col];
#pragma unroll
        for (int rt = 0; rt < 4; ++rt) {
            int rbase = row0 + (rt << 4) + (kb << 2);  // C: row=4*(lane>>4)+reg
#pragma unroll
            for (int j = 0; j < 4; ++j) {
                int rr = rbase + j;
                if (rr < NN)
                    dst[(size_t)rr * 128 + col] = (_Float16)(acc[sl][rt][j] + b);
            }
        }
    }
}

// ---- layer-2 dual GEMM: t2 = h1@Wl2, r2 = h1@Wr2  (K=128, M=64) -------------
// Block = 64 rows; A tile 16KB LDS; waves 0,1 -> t2, 2,3 -> r2; 2 slices/wave.

__global__ __launch_bounds__(256) void k_gemm_dual2(
        const _Float16* __restrict__ A,
        const _Float16* __restrict__ W1H, const _Float16* __restrict__ W1L,
        const _Float16* __restrict__ W2H, const _Float16* __restrict__ W2L,
        _Float16* __restrict__ T, _Float16* __restrict__ R) {
    __shared__ char As[64 * 256];              // 64 rows x 128 fp16, swizzled
    const int t = threadIdx.x;
    const int wave = t >> 6, lane = t & 63;
    const int r = lane & 15, kb = lane >> 4;
    const int row0 = blockIdx.x << 6;

#pragma unroll
    for (int j = 0; j < 4; ++j) {              // stage: 4 x 16B per thread
        int id = t + (j << 8);
        int row = id >> 4, c16 = id & 15;
        int gr = row0 + row;
        h8v v = (gr < NN) ? *(const h8v*)&A[(size_t)gr * 128 + (c16 << 3)]
                          : h8zero();
        *(h8v*)&As[row * 256 + (((c16 << 4)) ^ ((row & 7) << 4))] = v;
    }
    __syncthreads();

    const int sel = wave >> 1;                 // 0 -> T, 1 -> R
    const _Float16* __restrict__ WH = sel ? W2H : W1H;
    const _Float16* __restrict__ WL = sel ? W2L : W1L;
    _Float16* __restrict__ dst = sel ? R : T;
    const int colbase = (wave & 1) << 5;       // 32 cols per wave

    f32x4 acc[2][4];
#pragma unroll
    for (int sl = 0; sl < 2; ++sl)
#pragma unroll
        for (int rt = 0; rt < 4; ++rt) acc[sl][rt] = (f32x4){0.f, 0.f, 0.f, 0.f};

#pragma unroll
    for (int k = 0; k < 4; ++k) {
        h8v a[4];
#pragma unroll
        for (int rt = 0; rt < 4; ++rt) {
            int row = (rt << 4) + r;
            a[rt] = *(const h8v*)&As[row * 256 +
                                     (((k << 6) + (kb << 4)) ^ ((row & 7) << 4))];
        }
#pragma unroll
        for (int sl = 0; sl < 2; ++sl) {
            size_t woff = (size_t)(colbase + (sl << 4) + r) * 128 + (k << 5) + (kb << 3);
            h8v wh = *(const h8v*)&WH[woff];
            h8v wl = *(const h8v*)&WL[woff];
#pragma unroll
            for (int rt = 0; rt < 4; ++rt) {
                acc[sl][rt] = __builtin_amdgcn_mfma_f32_16x16x32_f16(a[rt], wh, acc[sl][rt], 0, 0, 0);
                acc[sl][rt] = __builtin_amdgcn_mfma_f32_16x16x32_f16(a[rt], wl, acc[sl][rt], 0, 0, 0);
            }
        }
    }
#pragma unroll
    for (int sl = 0; sl < 2; ++sl) {
        int col = colbase + (sl << 4) + r;
#pragma unroll
        for (int rt = 0; rt < 4; ++rt) {
            int rbase = row0 + (rt << 4) + (kb << 2);
#pragma unroll
            for (int j = 0; j < 4; ++j) {
                int rr = rbase + j;
                if (rr < NN)
                    dst[(size_t)rr * 64 + col] = (_Float16)acc[sl][rt][j];
            }
        }
    }
}

// ------- Aggregation 1: h1 = fp16(relu(mean(t1[src]) + bl1 + r1)) -------------
// one wave per node; two 32-lane halves, h4v (8B) loads, 2 neighbors/step.

__global__ __launch_bounds__(256) void k_aggr1(const _Float16* __restrict__ t1,
                                               const _Float16* __restrict__ r1,
                                               const int* __restrict__ rowp,
                                               const int* __restrict__ counts,
                                               const int* __restrict__ col,
                                               const float* __restrict__ bl1,
                                               _Float16* __restrict__ h1) {
    int node = blockIdx.x * 4 + (threadIdx.x >> 6);
    int lane = threadIdx.x & 63;
    if (node >= NN) return;
    int half = lane >> 5, sl = lane & 31;
    int e0 = rowp[node], cnt = counts[node];
    float a0 = 0.f, a1 = 0.f, a2 = 0.f, a3 = 0.f;
    const h4v* T = (const h4v*)t1;                 // 32 h4v per row
    for (int base = 0; base < cnt; base += 64) {
        int m = cnt - base; if (m > 64) m = 64;
        int myS = (base + lane < cnt) ? col[e0 + base + lane] : 0;
        int i = 0;
        for (; i + 8 <= m; i += 8) {
            int s0 = __shfl(myS, i + 0 + half), s1 = __shfl(myS, i + 2 + half);
            int s2 = __shfl(myS, i + 4 + half), s3 = __shfl(myS, i + 6 + half);
            h4v v0 = T[(size_t)s0 * 32 + sl], v1 = T[(size_t)s1 * 32 + sl];
            h4v v2 = T[(size_t)s2 * 32 + sl], v3 = T[(size_t)s3 * 32 + sl];
            a0 += (float)v0[0] + (float)v1[0] + (float)v2[0] + (float)v3[0];
            a1 += (float)v0[1] + (float)v1[1] + (float)v2[1] + (float)v3[1];
            a2 += (float)v0[2] + (float)v1[2] + (float)v2[2] + (float)v3[2];
            a3 += (float)v0[3] + (float)v1[3] + (float)v2[3] + (float)v3[3];
        }
        for (; i < m; i += 2) {
            if (i + half < m) {
                int s = __shfl(myS, i + half);
                h4v v = T[(size_t)s * 32 + sl];
                a0 += (float)v[0]; a1 += (float)v[1];
                a2 += (float)v[2]; a3 += (float)v[3];
            }
        }
    }
    a0 += __shfl_xor(a0, 32); a1 += __shfl_xor(a1, 32);
    a2 += __shfl_xor(a2, 32); a3 += __shfl_xor(a3, 32);
    float di = (cnt > 0) ? 1.0f / (float)cnt : 0.0f;
    h4v rr = ((const h4v*)r1)[(size_t)node * 32 + sl];
    float4 bb = ((const float4*)bl1)[sl];
    if (half == 0) {
        h4v h;
        h[0] = (_Float16)fmaxf(fmaf(a0, di, bb.x + (float)rr[0]), 0.0f);
        h[1] = (_Float16)fmaxf(fmaf(a1, di, bb.y + (float)rr[1]), 0.0f);
        h[2] = (_Float16)fmaxf(fmaf(a2, di, bb.z + (float)rr[2]), 0.0f);
        h[3] = (_Float16)fmaxf(fmaf(a3, di, bb.w + (float)rr[3]), 0.0f);
        ((h4v*)h1)[(size_t)node * 32 + sl] = h;
    }
}

// ------- Aggregation 2 + L2 normalize -----------------------------------------

__global__ __launch_bounds__(256) void k_aggr2(const _Float16* __restrict__ t2,
                                               const _Float16* __restrict__ r2,
                                               const int* __restrict__ rowp,
                                               const int* __restrict__ counts,
                                               const int* __restrict__ col,
                                               const float* __restrict__ bl2,
                                               float* __restrict__ out) {
    int node = blockIdx.x * 4 + (threadIdx.x >> 6);
    int lane = threadIdx.x & 63;
    if (node >= NN) return;
    int half = lane >> 5, sl = lane & 31;
    int e0 = rowp[node], cnt = counts[node];
    float ax = 0.f, ay = 0.f;
    const h2v* T = (const h2v*)t2;
    for (int base = 0; base < cnt; base += 64) {
        int m = cnt - base; if (m > 64) m = 64;
        int myS = (base + lane < cnt) ? col[e0 + base + lane] : 0;
        int i = 0;
        for (; i + 8 <= m; i += 8) {
            int s0 = __shfl(myS, i + 0 + half), s1 = __shfl(myS, i + 2 + half);
            int s2 = __shfl(myS, i + 4 + half), s3 = __shfl(myS, i + 6 + half);
            h2v v0 = T[(size_t)s0 * 32 + sl], v1 = T[(size_t)s1 * 32 + sl];
            h2v v2 = T[(size_t)s2 * 32 + sl], v3 = T[(size_t)s3 * 32 + sl];
            ax += (float)v0[0] + (float)v1[0] + (float)v2[0] + (float)v3[0];
            ay += (float)v0[1] + (float)v1[1] + (float)v2[1] + (float)v3[1];
        }
        for (; i < m; i += 2) {
            if (i + half < m) {
                int s = __shfl(myS, i + half);
                h2v v = T[(size_t)s * 32 + sl];
                ax += (float)v[0]; ay += (float)v[1];
            }
        }
    }
    ax += __shfl_xor(ax, 32);
    ay += __shfl_xor(ay, 32);
    float di = (cnt > 0) ? 1.0f / (float)cnt : 0.0f;
    h2v rr = ((const h2v*)r2)[(size_t)node * 32 + sl];
    float2 bb = ((const float2*)bl2)[sl];
    float v0 = fmaf(ax, di, bb.x + (float)rr[0]);
    float v1 = fmaf(ay, di, bb.y + (float)rr[1]);
    float ss = v0 * v0 + v1 * v1;
#pragma unroll
    for (int off = 16; off > 0; off >>= 1) ss += __shfl_xor(ss, off);
    float inv = 1.0f / fmaxf(sqrtf(ss), 1e-12f);
    if (half == 0)
        ((float2*)out)[(size_t)node * 32 + sl] = make_float2(v0 * inv, v1 * inv);
}

// ---------------- launch ----------------

extern "C" void kernel_launch(void* const* d_in, const int* in_sizes, int n_in,
                              void* d_out, int out_size, void* d_ws, size_t ws_size,
                              hipStream_t stream) {
    const float* x    = (const float*)d_in[0];
    const int*   ei   = (const int*)d_in[1];
    const float* Wpre = (const float*)d_in[2];
    const float* bpre = (const float*)d_in[3];
    const float* Wl1  = (const float*)d_in[4];
    const float* bl1  = (const float*)d_in[5];
    const float* Wr1  = (const float*)d_in[6];
    const float* Wl2  = (const float*)d_in[7];
    const float* bl2  = (const float*)d_in[8];
    const float* Wr2  = (const float*)d_in[9];
    float* out = (float*)d_out;

    char* w = (char*)d_ws;
    int* counts = (int*)w;  w += (size_t)NN * 4;
    int* cursor = (int*)w;  w += (size_t)NN * 4;
    int* rowp   = (int*)w;  w += (size_t)NN * 4;
    int* bsums  = (int*)w;  w += 256;
    int* col    = (int*)w;  w += (size_t)EE * 4;
    _Float16* WAH  = (_Float16*)w; w += (size_t)256 * 128 * 2;
    _Float16* WAL  = (_Float16*)w; w += (size_t)256 * 128 * 2;
    _Float16* WBH  = (_Float16*)w; w += (size_t)256 * 128 * 2;
    _Float16* WBL  = (_Float16*)w; w += (size_t)256 * 128 * 2;
    float*    bA   = (float*)w;    w += 128 * 4;
    float*    bB   = (float*)w;    w += 128 * 4;
    _Float16* W2lH = (_Float16*)w; w += (size_t)128 * 64 * 2;
    _Float16* W2lL = (_Float16*)w; w += (size_t)128 * 64 * 2;
    _Float16* W2rH = (_Float16*)w; w += (size_t)128 * 64 * 2;
    _Float16* W2rL = (_Float16*)w; w += (size_t)128 * 64 * 2;
    _Float16* xh   = (_Float16*)w; w += (size_t)NN * 256 * 2;   // 25.6MB
    _Float16* t1   = (_Float16*)w; w += (size_t)NN * 128 * 2;   // 12.8MB
    _Float16* r1   = (_Float16*)w; w += (size_t)NN * 128 * 2;
    _Float16* h1   = (_Float16*)w; w += (size_t)NN * 128 * 2;
    _Float16* t2   = (_Float16*)w; w += (size_t)NN * 64 * 2;
    _Float16* r2   = (_Float16*)w; w += (size_t)NN * 64 * 2;

    hipMemsetAsync(counts, 0, (size_t)NN * 8, stream);    // counts + cursor

    dim3 b256(256);
    dim3 gE((EE + 255) / 256);
    k_count<<<gE, b256, 0, stream>>>(ei, counts);
    k_scan_a<<<dim3(NBLK), b256, 0, stream>>>(counts, bsums);
    k_scan_b<<<dim3(1), dim3(64), 0, stream>>>(bsums);
    k_scan_c<<<dim3(NBLK), b256, 0, stream>>>(counts, bsums, rowp);
    k_scatter<<<gE, b256, 0, stream>>>(ei, rowp, cursor, col);

    k_cvt<<<dim3(NN * 256 / 4 / 256), b256, 0, stream>>>(x, xh, NN * 256 / 4);
    k_prep<<<dim3(321), b256, 0, stream>>>(Wpre, bpre, Wl1, Wr1, Wl2, Wr2,
                                           WAH, WAL, WBH, WBL, bA, bB,
                                           W2lH, W2lL, W2rH, W2rL);

    k_gemm_fused<<<dim3(NRG64), b256, 0, stream>>>(xh, WAH, WAL, WBH, WBL,
                                                   bA, bB, t1, r1);
    k_aggr1<<<dim3((NN + 3) / 4), b256, 0, stream>>>(t1, r1, rowp, counts, col, bl1, h1);
    k_gemm_dual2<<<dim3(NRG64), b256, 0, stream>>>(h1, W2lH, W2lL, W2rH, W2rL, t2, r2);
    k_aggr2<<<dim3((NN + 3) / 4), b256, 0, stream>>>(t2, r2, rowp, counts, col, bl2, out);
}

// Round 12
// 293.630 us; speedup vs baseline: 1.1539x; 1.0636x over previous
//
#include <hip/hip_runtime.h>

// GraphSAGE 2-layer pipeline, fp16 activations + MFMA f16 (weights hi+lo 2-term).
// linear_pre fused into conv_first:  t1 = x@(Wpre@Wl1)+b_pre@Wl1, r1 = x@(Wpre@Wr1)+b_pre@Wr1.
// Round-11 (resubmit; container infra failure): SWAPPED MFMA operands
// (mfma(W,A) -> D transposed) so the epilogue writes h4v 8B chunks
// (16 stores/thread) instead of 64 scalar 2B stores (round-10 failure:
// WRITE_SIZE 61.6MB vs 25.6 logical, store-issue bound). Also: fp32->fp16
// convert fused into the GEMM stage phase (k_cvt deleted).
// N=50000, E=600000, edge_index int32.

#define NN   50000
#define EE   600000
#define NBLK 49          // ceil(NN/1024)
#define NRG64 782        // ceil(NN/64)

typedef __attribute__((ext_vector_type(8))) _Float16 h8v;
typedef __attribute__((ext_vector_type(4))) _Float16 h4v;
typedef __attribute__((ext_vector_type(2))) _Float16 h2v;
typedef __attribute__((ext_vector_type(8))) short short8v;
typedef __attribute__((ext_vector_type(4))) float f32x4;

__device__ inline h8v h8zero() {
    return __builtin_bit_cast(h8v, (short8v){0,0,0,0,0,0,0,0});
}

__device__ inline h8v cvt8f(float4 f0, float4 f1) {
    h8v a;
    a[0] = (_Float16)f0.x; a[1] = (_Float16)f0.y;
    a[2] = (_Float16)f0.z; a[3] = (_Float16)f0.w;
    a[4] = (_Float16)f1.x; a[5] = (_Float16)f1.y;
    a[6] = (_Float16)f1.z; a[7] = (_Float16)f1.w;
    return a;
}

// ---------------- CSR build ----------------

__global__ __launch_bounds__(256) void k_count(const int* __restrict__ ei,
                                               int* __restrict__ counts) {
    int e = blockIdx.x * 256 + threadIdx.x;
    if (e < EE) atomicAdd(&counts[ei[EE + e]], 1);
}

__global__ __launch_bounds__(256) void k_scan_a(const int* __restrict__ counts,
                                                int* __restrict__ bsums) {
    int b = blockIdx.x, t = threadIdx.x;
    int idx = b * 1024 + t * 4;
    int s = 0;
#pragma unroll
    for (int j = 0; j < 4; ++j)
        if (idx + j < NN) s += counts[idx + j];
#pragma unroll
    for (int off = 32; off > 0; off >>= 1) s += __shfl_down(s, off);
    __shared__ int ls[4];
    if ((t & 63) == 0) ls[t >> 6] = s;
    __syncthreads();
    if (t == 0) bsums[b] = ls[0] + ls[1] + ls[2] + ls[3];
}

__global__ void k_scan_b(int* __restrict__ bsums) {
    int t = threadIdx.x;                       // 64 threads
    int v = (t < NBLK) ? bsums[t] : 0;
    int orig = v;
#pragma unroll
    for (int off = 1; off < 64; off <<= 1) {
        int u = __shfl_up(v, off);
        if (t >= off) v += u;
    }
    if (t < NBLK) bsums[t] = v - orig;          // exclusive
}

__global__ __launch_bounds__(256) void k_scan_c(const int* __restrict__ counts,
                                                const int* __restrict__ bsums,
                                                int* __restrict__ rowp) {
    int b = blockIdx.x, t = threadIdx.x;
    int lane = t & 63, wave = t >> 6;
    int idx = b * 1024 + t * 4;
    int c[4], s = 0;
#pragma unroll
    for (int j = 0; j < 4; ++j) {
        c[j] = (idx + j < NN) ? counts[idx + j] : 0;
        s += c[j];
    }
    int sv = s;
#pragma unroll
    for (int off = 1; off < 64; off <<= 1) {
        int u = __shfl_up(sv, off);
        if (lane >= off) sv += u;
    }
    __shared__ int lsum[4];
    if (lane == 63) lsum[wave] = sv;
    __syncthreads();
    int woff = 0;
    for (int wv = 0; wv < wave; ++wv) woff += lsum[wv];
    int base = bsums[b] + woff + (sv - s);
#pragma unroll
    for (int j = 0; j < 4; ++j) {
        if (idx + j < NN) { rowp[idx + j] = base; base += c[j]; }
    }
}

__global__ __launch_bounds__(256) void k_scatter(const int* __restrict__ ei,
                                                 const int* __restrict__ rowp,
                                                 int* __restrict__ cursor,
                                                 int* __restrict__ col) {
    int e = blockIdx.x * 256 + threadIdx.x;
    if (e < EE) {
        int d = ei[EE + e];
        int p = atomicAdd(&cursor[d], 1);
        col[rowp[d] + p] = ei[e];
    }
}

// ---- prep: fused layer-1 weights (WA=Wpre@Wl1, WB=Wpre@Wr1, transposed hi/lo
// ---- fp16) + bias rows (fp32) + layer-2 packed transposed hi/lo weights.

__global__ __launch_bounds__(256) void k_prep(const float* __restrict__ Wpre,
                                              const float* __restrict__ bpre,
                                              const float* __restrict__ Wl1,
                                              const float* __restrict__ Wr1,
                                              const float* __restrict__ Wl2,
                                              const float* __restrict__ Wr2,
                                              _Float16* __restrict__ WAH,
                                              _Float16* __restrict__ WAL,
                                              _Float16* __restrict__ WBH,
                                              _Float16* __restrict__ WBL,
                                              float* __restrict__ bA,
                                              float* __restrict__ bB,
                                              _Float16* __restrict__ W2lH,
                                              _Float16* __restrict__ W2lL,
                                              _Float16* __restrict__ W2rH,
                                              _Float16* __restrict__ W2rL) {
    int idx = blockIdx.x * 256 + threadIdx.x;     // 321*256 = 82176 exact
    if (idx < 65792) {                            // 2*257*128: layer-1 fuse
        int which = idx / (257 * 128);
        int rem = idx - which * 257 * 128;
        int i = rem >> 7, j = rem & 127;
        const float* W = which ? Wr1 : Wl1;
        float s = 0.f;
        if (i < 256) {
#pragma unroll 4
            for (int k = 0; k < 128; ++k) s += Wpre[i * 128 + k] * W[k * 128 + j];
            _Float16 h = (_Float16)s;
            _Float16 l = (_Float16)(s - (float)h);
            if (which) { WBH[j * 256 + i] = h; WBL[j * 256 + i] = l; }
            else       { WAH[j * 256 + i] = h; WAL[j * 256 + i] = l; }
        } else {
#pragma unroll 4
            for (int k = 0; k < 128; ++k) s += bpre[k] * W[k * 128 + j];
            if (which) bB[j] = s; else bA[j] = s;
        }
    } else {                                      // 2*8192: layer-2 pack
        int idx2 = idx - 65792;
        int which = idx2 >> 13;
        int rem = idx2 & 8191;
        int k = rem >> 6, m = rem & 63;
        float w = (which ? Wr2 : Wl2)[rem];
        _Float16 h = (_Float16)w;
        _Float16 l = (_Float16)(w - (float)h);
        if (which) { W2rH[m * 128 + k] = h; W2rL[m * 128 + k] = l; }
        else       { W2lH[m * 128 + k] = h; W2lL[m * 128 + k] = l; }
    }
}

// ---- fused dual GEMM: t1 = x@WA + bA, r1 = x@WB + bB  (K=256) ---------------
// Block = 64 rows; fp32 x converted in-register during stage; A tile in LDS
// (swizzled). Waves 0,1 -> t1, waves 2,3 -> r1; 4 col-slices of 16 per wave.
// MFMA operands SWAPPED: D-lane = C-row, D-regs = 4 consecutive C-cols.

__global__ __launch_bounds__(256) void k_gemm_fused(
        const float* __restrict__ x,
        const _Float16* __restrict__ WAH, const _Float16* __restrict__ WAL,
        const _Float16* __restrict__ WBH, const _Float16* __restrict__ WBL,
        const float* __restrict__ bA, const float* __restrict__ bB,
        _Float16* __restrict__ t1, _Float16* __restrict__ r1) {
    __shared__ char As[64 * 512];              // 64 rows x 256 fp16, swizzled
    const int t = threadIdx.x;
    const int wave = t >> 6, lane = t & 63;
    const int r = lane & 15, kb = lane >> 4;
    const int row0 = blockIdx.x << 6;

#pragma unroll
    for (int j = 0; j < 8; ++j) {              // stage: cvt fp32->fp16 in-reg
        int id = t + (j << 8);
        int row = id >> 5, c16 = id & 31;
        int gr = row0 + row;
        h8v v;
        if (gr < NN) {
            float4 f0 = *(const float4*)&x[(size_t)gr * 256 + (c16 << 3)];
            float4 f1 = *(const float4*)&x[(size_t)gr * 256 + (c16 << 3) + 4];
            v = cvt8f(f0, f1);
        } else {
            v = h8zero();
        }
        *(h8v*)&As[row * 512 + (((c16 << 4)) ^ ((row & 7) << 4))] = v;
    }
    __syncthreads();

    const int sel = wave >> 1;                 // 0 -> t1, 1 -> r1
    const _Float16* __restrict__ WH = sel ? WBH : WAH;
    const _Float16* __restrict__ WL = sel ? WBL : WAL;
    _Float16* __restrict__ dst = sel ? r1 : t1;
    const float* __restrict__ bias = sel ? bB : bA;
    const int colbase = (wave & 1) << 6;       // 64 cols per wave

    f32x4 acc[4][4];
#pragma unroll
    for (int sl = 0; sl < 4; ++sl)
#pragma unroll
        for (int rt = 0; rt < 4; ++rt) acc[sl][rt] = (f32x4){0.f, 0.f, 0.f, 0.f};

#pragma unroll
    for (int k = 0; k < 8; ++k) {
        h8v a[4];
#pragma unroll
        for (int rt = 0; rt < 4; ++rt) {
            int row = (rt << 4) + r;
            a[rt] = *(const h8v*)&As[row * 512 +
                                     (((k << 6) + (kb << 4)) ^ ((row & 7) << 4))];
        }
#pragma unroll
        for (int sl = 0; sl < 4; ++sl) {
            size_t woff = (size_t)(colbase + (sl << 4) + r) * 256 + (k << 5) + (kb << 3);
            h8v wh = *(const h8v*)&WH[woff];
            h8v wl = *(const h8v*)&WL[woff];
#pragma unroll
            for (int rt = 0; rt < 4; ++rt) {   // swapped operands -> D transposed
                acc[sl][rt] = __builtin_amdgcn_mfma_f32_16x16x32_f16(wh, a[rt], acc[sl][rt], 0, 0, 0);
                acc[sl][rt] = __builtin_amdgcn_mfma_f32_16x16x32_f16(wl, a[rt], acc[sl][rt], 0, 0, 0);
            }
        }
    }
    // D layout (swapped): C-row = rt*16 + (lane&15), C-cols = sl*16 + 4*kb + j
#pragma unroll
    for (int sl = 0; sl < 4; ++sl) {
        int col4 = colbase + (sl << 4) + (kb << 2);
        float4 b4 = *(const float4*)&bias[col4];
#pragma unroll
        for (int rt = 0; rt < 4; ++rt) {
            int row = row0 + (rt << 4) + r;
            if (row < NN) {
                h4v o;
                o[0] = (_Float16)(acc[sl][rt][0] + b4.x);
                o[1] = (_Float16)(acc[sl][rt][1] + b4.y);
                o[2] = (_Float16)(acc[sl][rt][2] + b4.z);
                o[3] = (_Float16)(acc[sl][rt][3] + b4.w);
                *(h4v*)&dst[(size_t)row * 128 + col4] = o;
            }
        }
    }
}

// ---- layer-2 dual GEMM: t2 = h1@Wl2, r2 = h1@Wr2  (K=128, M=64) -------------
// Block = 64 rows; A tile 16KB LDS; waves 0,1 -> t2, 2,3 -> r2; swapped MFMA.

__global__ __launch_bounds__(256) void k_gemm_dual2(
        const _Float16* __restrict__ A,
        const _Float16* __restrict__ W1H, const _Float16* __restrict__ W1L,
        const _Float16* __restrict__ W2H, const _Float16* __restrict__ W2L,
        _Float16* __restrict__ T, _Float16* __restrict__ R) {
    __shared__ char As[64 * 256];              // 64 rows x 128 fp16, swizzled
    const int t = threadIdx.x;
    const int wave = t >> 6, lane = t & 63;
    const int r = lane & 15, kb = lane >> 4;
    const int row0 = blockIdx.x << 6;

#pragma unroll
    for (int j = 0; j < 4; ++j) {              // stage: 4 x 16B per thread
        int id = t + (j << 8);
        int row = id >> 4, c16 = id & 15;
        int gr = row0 + row;
        h8v v = (gr < NN) ? *(const h8v*)&A[(size_t)gr * 128 + (c16 << 3)]
                          : h8zero();
        *(h8v*)&As[row * 256 + (((c16 << 4)) ^ ((row & 7) << 4))] = v;
    }
    __syncthreads();

    const int sel = wave >> 1;                 // 0 -> T, 1 -> R
    const _Float16* __restrict__ WH = sel ? W2H : W1H;
    const _Float16* __restrict__ WL = sel ? W2L : W1L;
    _Float16* __restrict__ dst = sel ? R : T;
    const int colbase = (wave & 1) << 5;       // 32 cols per wave

    f32x4 acc[2][4];
#pragma unroll
    for (int sl = 0; sl < 2; ++sl)
#pragma unroll
        for (int rt = 0; rt < 4; ++rt) acc[sl][rt] = (f32x4){0.f, 0.f, 0.f, 0.f};

#pragma unroll
    for (int k = 0; k < 4; ++k) {
        h8v a[4];
#pragma unroll
        for (int rt = 0; rt < 4; ++rt) {
            int row = (rt << 4) + r;
            a[rt] = *(const h8v*)&As[row * 256 +
                                     (((k << 6) + (kb << 4)) ^ ((row & 7) << 4))];
        }
#pragma unroll
        for (int sl = 0; sl < 2; ++sl) {
            size_t woff = (size_t)(colbase + (sl << 4) + r) * 128 + (k << 5) + (kb << 3);
            h8v wh = *(const h8v*)&WH[woff];
            h8v wl = *(const h8v*)&WL[woff];
#pragma unroll
            for (int rt = 0; rt < 4; ++rt) {   // swapped operands
                acc[sl][rt] = __builtin_amdgcn_mfma_f32_16x16x32_f16(wh, a[rt], acc[sl][rt], 0, 0, 0);
                acc[sl][rt] = __builtin_amdgcn_mfma_f32_16x16x32_f16(wl, a[rt], acc[sl][rt], 0, 0, 0);
            }
        }
    }
#pragma unroll
    for (int sl = 0; sl < 2; ++sl) {
        int col4 = colbase + (sl << 4) + (kb << 2);
#pragma unroll
        for (int rt = 0; rt < 4; ++rt) {
            int row = row0 + (rt << 4) + r;
            if (row < NN) {
                h4v o;
                o[0] = (_Float16)acc[sl][rt][0];
                o[1] = (_Float16)acc[sl][rt][1];
                o[2] = (_Float16)acc[sl][rt][2];
                o[3] = (_Float16)acc[sl][rt][3];
                *(h4v*)&dst[(size_t)row * 64 + col4] = o;
            }
        }
    }
}

// ------- Aggregation 1: h1 = fp16(relu(mean(t1[src]) + bl1 + r1)) -------------
// one wave per node; two 32-lane halves, h4v (8B) loads, 2 neighbors/step.

__global__ __launch_bounds__(256) void k_aggr1(const _Float16* __restrict__ t1,
                                               const _Float16* __restrict__ r1,
                                               const int* __restrict__ rowp,
                                               const int* __restrict__ counts,
                                               const int* __restrict__ col,
                                               const float* __restrict__ bl1,
                                               _Float16* __restrict__ h1) {
    int node = blockIdx.x * 4 + (threadIdx.x >> 6);
    int lane = threadIdx.x & 63;
    if (node >= NN) return;
    int half = lane >> 5, sl = lane & 31;
    int e0 = rowp[node], cnt = counts[node];
    float a0 = 0.f, a1 = 0.f, a2 = 0.f, a3 = 0.f;
    const h4v* T = (const h4v*)t1;                 // 32 h4v per row
    for (int base = 0; base < cnt; base += 64) {
        int m = cnt - base; if (m > 64) m = 64;
        int myS = (base + lane < cnt) ? col[e0 + base + lane] : 0;
        int i = 0;
        for (; i + 8 <= m; i += 8) {
            int s0 = __shfl(myS, i + 0 + half), s1 = __shfl(myS, i + 2 + half);
            int s2 = __shfl(myS, i + 4 + half), s3 = __shfl(myS, i + 6 + half);
            h4v v0 = T[(size_t)s0 * 32 + sl], v1 = T[(size_t)s1 * 32 + sl];
            h4v v2 = T[(size_t)s2 * 32 + sl], v3 = T[(size_t)s3 * 32 + sl];
            a0 += (float)v0[0] + (float)v1[0] + (float)v2[0] + (float)v3[0];
            a1 += (float)v0[1] + (float)v1[1] + (float)v2[1] + (float)v3[1];
            a2 += (float)v0[2] + (float)v1[2] + (float)v2[2] + (float)v3[2];
            a3 += (float)v0[3] + (float)v1[3] + (float)v2[3] + (float)v3[3];
        }
        for (; i < m; i += 2) {
            if (i + half < m) {
                int s = __shfl(myS, i + half);
                h4v v = T[(size_t)s * 32 + sl];
                a0 += (float)v[0]; a1 += (float)v[1];
                a2 += (float)v[2]; a3 += (float)v[3];
            }
        }
    }
    a0 += __shfl_xor(a0, 32); a1 += __shfl_xor(a1, 32);
    a2 += __shfl_xor(a2, 32); a3 += __shfl_xor(a3, 32);
    float di = (cnt > 0) ? 1.0f / (float)cnt : 0.0f;
    h4v rr = ((const h4v*)r1)[(size_t)node * 32 + sl];
    float4 bb = ((const float4*)bl1)[sl];
    if (half == 0) {
        h4v h;
        h[0] = (_Float16)fmaxf(fmaf(a0, di, bb.x + (float)rr[0]), 0.0f);
        h[1] = (_Float16)fmaxf(fmaf(a1, di, bb.y + (float)rr[1]), 0.0f);
        h[2] = (_Float16)fmaxf(fmaf(a2, di, bb.z + (float)rr[2]), 0.0f);
        h[3] = (_Float16)fmaxf(fmaf(a3, di, bb.w + (float)rr[3]), 0.0f);
        ((h4v*)h1)[(size_t)node * 32 + sl] = h;
    }
}

// ------- Aggregation 2 + L2 normalize -----------------------------------------

__global__ __launch_bounds__(256) void k_aggr2(const _Float16* __restrict__ t2,
                                               const _Float16* __restrict__ r2,
                                               const int* __restrict__ rowp,
                                               const int* __restrict__ counts,
                                               const int* __restrict__ col,
                                               const float* __restrict__ bl2,
                                               float* __restrict__ out) {
    int node = blockIdx.x * 4 + (threadIdx.x >> 6);
    int lane = threadIdx.x & 63;
    if (node >= NN) return;
    int half = lane >> 5, sl = lane & 31;
    int e0 = rowp[node], cnt = counts[node];
    float ax = 0.f, ay = 0.f;
    const h2v* T = (const h2v*)t2;
    for (int base = 0; base < cnt; base += 64) {
        int m = cnt - base; if (m > 64) m = 64;
        int myS = (base + lane < cnt) ? col[e0 + base + lane] : 0;
        int i = 0;
        for (; i + 8 <= m; i += 8) {
            int s0 = __shfl(myS, i + 0 + half), s1 = __shfl(myS, i + 2 + half);
            int s2 = __shfl(myS, i + 4 + half), s3 = __shfl(myS, i + 6 + half);
            h2v v0 = T[(size_t)s0 * 32 + sl], v1 = T[(size_t)s1 * 32 + sl];
            h2v v2 = T[(size_t)s2 * 32 + sl], v3 = T[(size_t)s3 * 32 + sl];
            ax += (float)v0[0] + (float)v1[0] + (float)v2[0] + (float)v3[0];
            ay += (float)v0[1] + (float)v1[1] + (float)v2[1] + (float)v3[1];
        }
        for (; i < m; i += 2) {
            if (i + half < m) {
                int s = __shfl(myS, i + half);
                h2v v = T[(size_t)s * 32 + sl];
                ax += (float)v[0]; ay += (float)v[1];
            }
        }
    }
    ax += __shfl_xor(ax, 32);
    ay += __shfl_xor(ay, 32);
    float di = (cnt > 0) ? 1.0f / (float)cnt : 0.0f;
    h2v rr = ((const h2v*)r2)[(size_t)node * 32 + sl];
    float2 bb = ((const float2*)bl2)[sl];
    float v0 = fmaf(ax, di, bb.x + (float)rr[0]);
    float v1 = fmaf(ay, di, bb.y + (float)rr[1]);
    float ss = v0 * v0 + v1 * v1;
#pragma unroll
    for (int off = 16; off > 0; off >>= 1) ss += __shfl_xor(ss, off);
    float inv = 1.0f / fmaxf(sqrtf(ss), 1e-12f);
    if (half == 0)
        ((float2*)out)[(size_t)node * 32 + sl] = make_float2(v0 * inv, v1 * inv);
}

// ---------------- launch ----------------

extern "C" void kernel_launch(void* const* d_in, const int* in_sizes, int n_in,
                              void* d_out, int out_size, void* d_ws, size_t ws_size,
                              hipStream_t stream) {
    const float* x    = (const float*)d_in[0];
    const int*   ei   = (const int*)d_in[1];
    const float* Wpre = (const float*)d_in[2];
    const float* bpre = (const float*)d_in[3];
    const float* Wl1  = (const float*)d_in[4];
    const float* bl1  = (const float*)d_in[5];
    const float* Wr1  = (const float*)d_in[6];
    const float* Wl2  = (const float*)d_in[7];
    const float* bl2  = (const float*)d_in[8];
    const float* Wr2  = (const float*)d_in[9];
    float* out = (float*)d_out;

    char* w = (char*)d_ws;
    int* counts = (int*)w;  w += (size_t)NN * 4;
    int* cursor = (int*)w;  w += (size_t)NN * 4;
    int* rowp   = (int*)w;  w += (size_t)NN * 4;
    int* bsums  = (int*)w;  w += 256;
    int* col    = (int*)w;  w += (size_t)EE * 4;
    _Float16* WAH  = (_Float16*)w; w += (size_t)256 * 128 * 2;
    _Float16* WAL  = (_Float16*)w; w += (size_t)256 * 128 * 2;
    _Float16* WBH  = (_Float16*)w; w += (size_t)256 * 128 * 2;
    _Float16* WBL  = (_Float16*)w; w += (size_t)256 * 128 * 2;
    float*    bA   = (float*)w;    w += 128 * 4;
    float*    bB   = (float*)w;    w += 128 * 4;
    _Float16* W2lH = (_Float16*)w; w += (size_t)128 * 64 * 2;
    _Float16* W2lL = (_Float16*)w; w += (size_t)128 * 64 * 2;
    _Float16* W2rH = (_Float16*)w; w += (size_t)128 * 64 * 2;
    _Float16* W2rL = (_Float16*)w; w += (size_t)128 * 64 * 2;
    _Float16* t1   = (_Float16*)w; w += (size_t)NN * 128 * 2;   // 12.8MB
    _Float16* r1   = (_Float16*)w; w += (size_t)NN * 128 * 2;
    _Float16* h1   = (_Float16*)w; w += (size_t)NN * 128 * 2;
    _Float16* t2   = (_Float16*)w; w += (size_t)NN * 64 * 2;
    _Float16* r2   = (_Float16*)w; w += (size_t)NN * 64 * 2;

    hipMemsetAsync(counts, 0, (size_t)NN * 8, stream);    // counts + cursor

    dim3 b256(256);
    dim3 gE((EE + 255) / 256);
    k_count<<<gE, b256, 0, stream>>>(ei, counts);
    k_scan_a<<<dim3(NBLK), b256, 0, stream>>>(counts, bsums);
    k_scan_b<<<dim3(1), dim3(64), 0, stream>>>(bsums);
    k_scan_c<<<dim3(NBLK), b256, 0, stream>>>(counts, bsums, rowp);
    k_scatter<<<gE, b256, 0, stream>>>(ei, rowp, cursor, col);

    k_prep<<<dim3(321), b256, 0, stream>>>(Wpre, bpre, Wl1, Wr1, Wl2, Wr2,
                                           WAH, WAL, WBH, WBL, bA, bB,
                                           W2lH, W2lL, W2rH, W2rL);

    k_gemm_fused<<<dim3(NRG64), b256, 0, stream>>>(x, WAH, WAL, WBH, WBL,
                                                   bA, bB, t1, r1);
    k_aggr1<<<dim3((NN + 3) / 4), b256, 0, stream>>>(t1, r1, rowp, counts, col, bl1, h1);
    k_gemm_dual2<<<dim3(NRG64), b256, 0, stream>>>(h1, W2lH, W2lL, W2rH, W2rL, t2, r2);
    k_aggr2<<<dim3((NN + 3) / 4), b256, 0, stream>>>(t2, r2, rowp, counts, col, bl2, out);
}